// Round 1
// baseline (449.761 us; speedup 1.0000x reference)
//
#include <hip/hip_runtime.h>
#include <hip/hip_bf16.h>
#include <math.h>

// Problem constants (from reference): B=16, H=32, KV=8, D=128, BS=16, MAXLEN=4096
#define B_ 16
#define H_ 32
#define KVH_ 8
#define D_ 128
#define BS_ 16
#define NBLK_ 256
#define GQA_R 4          // H / KV
#define LOCALB 16        // LOCAL_BLOCKS
#define VSTRIDE 8        // VERT_STRIDE  (head_sliding_step = max(1, 8/32) = 1)

// K layout: [NB][KVH][D/4][BS][4] f32 -> K[t][d] at (((nb*8+kvh)*32 + d/4)*16 + t)*4 + d%4
// V layout: [NB][KVH][D][BS]   f32 -> V[d][t] at  ((nb*8+kvh)*128 + d)*16 + t
// Both blocks are 2048 floats per (nb,kvh).

template <int NSPLIT, bool DIRECT>
__global__ __launch_bounds__(256, 4) void sparse_attn_partial(
    const float* __restrict__ qg, const float* __restrict__ kc,
    const float* __restrict__ vc, const int* __restrict__ block_tables,
    const int* __restrict__ ctx_lens,
    float* __restrict__ po,   // [B,H,NSPLIT,D] unnormalized O partials
    float* __restrict__ pml,  // [B,H,NSPLIT,2] (m, l)
    float* __restrict__ out)  // used when DIRECT
{
  const int wid  = threadIdx.x >> 6;   // wave = head-in-group
  const int lane = threadIdx.x & 63;
  const int t    = lane >> 2;          // token 0..15
  const int c    = lane & 3;           // 32-dim chunk 0..3

  int bid = blockIdx.x;
  const int split = bid % NSPLIT; bid /= NSPLIT;
  const int kvh = bid % KVH_;
  const int b   = bid / KVH_;
  const int h   = kvh * GQA_R + wid;

  const int past_len = ctx_lens[b] - 1;
  const int q_pbid   = past_len >> 4;
  const int lo_start = max(0, q_pbid - (LOCALB - 1));
  const int nloc     = q_pbid - lo_start + 1;
  // vertical-stride residue: kp == -(h+1) mod 8
  const int v_res = (VSTRIDE - ((h + 1) & (VSTRIDE - 1))) & (VSTRIDE - 1);
  const int ndist = (lo_start > v_res) ? ((lo_start - v_res + 7) >> 3) : 0;
  const int ntot  = ndist + nloc;

  const int per = (ntot + NSPLIT - 1) / NSPLIT;
  const int i0  = split * per;
  const int i1  = min(ntot, i0 + per);

  // Q fragment: this lane's 32 dims [c*32, c*32+32)
  const float* qp = qg + ((size_t)(b * H_ + h)) * D_ + c * 32;
  float4 qf[8];
#pragma unroll
  for (int i = 0; i < 8; ++i) qf[i] = *(const float4*)(qp + i * 4);

  const float sm_scale = 0.08838834764831845f;  // 1/sqrt(128)
  float m_run = -INFINITY, l_run = 0.f, o0 = 0.f, o1 = 0.f;

  const int* bt = block_tables + b * NBLK_;

  for (int i = i0; i < i1; ++i) {
    const int kp = (i < ndist) ? (v_res + (i << 3)) : (lo_start + (i - ndist));
    const int nb = bt[kp];
    const float* kb = kc + (size_t)(nb * KVH_ + kvh) * 2048;
    const float* vb = vc + (size_t)(nb * KVH_ + kvh) * 2048;

    // ---- QK^T: lane computes partial dot over its 32 dims for token t ----
    float acc = 0.f;
#pragma unroll
    for (int ii = 0; ii < 8; ++ii) {
      float4 kk = *(const float4*)(kb + (c * 8 + ii) * 64 + t * 4);
      acc += qf[ii].x * kk.x + qf[ii].y * kk.y + qf[ii].z * kk.z + qf[ii].w * kk.w;
    }
    acc += __shfl_xor(acc, 1, 64);
    acc += __shfl_xor(acc, 2, 64);
    float s = acc * sm_scale;
    if (((kp << 4) + t) > past_len) s = -INFINITY;  // token-level causal

    // ---- online softmax (reduce across token groups: xor 4,8,16,32) ----
    float bm = s;
#pragma unroll
    for (int mk = 4; mk < 64; mk <<= 1) bm = fmaxf(bm, __shfl_xor(bm, mk, 64));
    const float m_new = fmaxf(m_run, bm);
    const float corr  = __expf(m_run - m_new);  // exp(-inf - finite) = 0
    const float p     = __expf(s - m_new);
    float psum = p;
#pragma unroll
    for (int mk = 4; mk < 64; mk <<= 1) psum += __shfl_xor(psum, mk, 64);
    l_run = l_run * corr + psum;
    m_run = m_new;
    o0 *= corr;
    o1 *= corr;

    // ---- PV: lane owns dims d0=lane, d1=lane+64 ----
    float pb[16];
#pragma unroll
    for (int tt = 0; tt < 16; ++tt) pb[tt] = __shfl(p, tt * 4, 64);
    const float* v0 = vb + lane * 16;
    const float* v1 = vb + (lane + 64) * 16;
#pragma unroll
    for (int ii = 0; ii < 4; ++ii) {
      float4 va = *(const float4*)(v0 + ii * 4);
      float4 vbq = *(const float4*)(v1 + ii * 4);
      o0 += pb[ii * 4 + 0] * va.x + pb[ii * 4 + 1] * va.y +
            pb[ii * 4 + 2] * va.z + pb[ii * 4 + 3] * va.w;
      o1 += pb[ii * 4 + 0] * vbq.x + pb[ii * 4 + 1] * vbq.y +
            pb[ii * 4 + 2] * vbq.z + pb[ii * 4 + 3] * vbq.w;
    }
  }

  if (DIRECT) {
    const float inv_l = 1.f / l_run;  // >=1 token always present when NSPLIT==1
    float* op = out + ((size_t)(b * H_ + h)) * D_;
    op[lane] = o0 * inv_l;
    op[lane + 64] = o1 * inv_l;
  } else {
    float* pop = po + ((size_t)((b * H_ + h) * NSPLIT + split)) * D_;
    pop[lane] = o0;
    pop[lane + 64] = o1;
    if (lane == 0) {
      float* pm = pml + ((size_t)((b * H_ + h) * NSPLIT + split)) * 2;
      pm[0] = m_run;
      pm[1] = l_run;
    }
  }
}

template <int NSPLIT>
__global__ __launch_bounds__(128) void sparse_attn_combine(
    const float* __restrict__ po, const float* __restrict__ pml,
    float* __restrict__ out)
{
  const int bh = blockIdx.x;   // 0 .. B*H-1
  const int d  = threadIdx.x;  // 0 .. 127
  const float* pm = pml + (size_t)bh * NSPLIT * 2;
  float m_g = -INFINITY;
#pragma unroll
  for (int s = 0; s < NSPLIT; ++s) m_g = fmaxf(m_g, pm[s * 2]);
  float L = 0.f, acc = 0.f;
  const float* pop = po + (size_t)bh * NSPLIT * D_ + d;
#pragma unroll
  for (int s = 0; s < NSPLIT; ++s) {
    const float ms = pm[s * 2];
    const float sc = (ms == -INFINITY) ? 0.f : __expf(ms - m_g);
    L += pm[s * 2 + 1] * sc;
    acc += pop[s * D_] * sc;
  }
  out[(size_t)bh * D_ + d] = acc / L;
}

extern "C" void kernel_launch(void* const* d_in, const int* in_sizes, int n_in,
                              void* d_out, int out_size, void* d_ws, size_t ws_size,
                              hipStream_t stream) {
  const float* q  = (const float*)d_in[0];
  const float* k  = (const float*)d_in[1];
  const float* v  = (const float*)d_in[2];
  const int* bt   = (const int*)d_in[3];
  const int* cl   = (const int*)d_in[4];
  // d_in[5] (pattern) is recomputed analytically on device.
  float* out = (float*)d_out;

  constexpr int NSPLIT = 8;
  const size_t needed = (size_t)B_ * H_ * NSPLIT * (D_ + 2) * sizeof(float);

  if (ws_size >= needed) {
    float* po  = (float*)d_ws;                       // [B,H,NSPLIT,D]
    float* pml = po + (size_t)B_ * H_ * NSPLIT * D_; // [B,H,NSPLIT,2]
    hipLaunchKernelGGL((sparse_attn_partial<NSPLIT, false>),
                       dim3(B_ * KVH_ * NSPLIT), dim3(256), 0, stream,
                       q, k, v, bt, cl, po, pml, out);
    hipLaunchKernelGGL((sparse_attn_combine<NSPLIT>),
                       dim3(B_ * H_), dim3(128), 0, stream, po, pml, out);
  } else {
    hipLaunchKernelGGL((sparse_attn_partial<1, true>),
                       dim3(B_ * KVH_), dim3(256), 0, stream,
                       q, k, v, bt, cl, nullptr, nullptr, out);
  }
}